// Round 2
// baseline (423.883 us; speedup 1.0000x reference)
//
#include <hip/hip_runtime.h>
#include <math.h>

#define NBLEND 24
#define HDIM 128
#define HHALF 64
#define MAX_STEPS 10
#define CVG_T 1e-5f
#define DVG_T 1.0f
#define EPS_B 1e-6f

typedef float v2f __attribute__((ext_vector_type(2)));

#if __has_builtin(__builtin_elementwise_fma)
#define VFMA(a, b, c) __builtin_elementwise_fma((a), (b), (c))
#else
__device__ __forceinline__ v2f VFMA(v2f a, v2f b, v2f c) {
    v2f r; r.x = fmaf(a.x, b.x, c.x); r.y = fmaf(a.y, b.y, c.y); return r;
}
#endif

__device__ __forceinline__ float softplus_f(float x) {
    // jax.nn.softplus: max(x,0) + log1p(exp(-|x|)), numerically stable
    float e = __expf(-fabsf(x));
    return fmaxf(x, 0.0f) + __logf(1.0f + e);
}

// One g(x) evaluation for a single point (one thread).
// H is processed in two 64-wide chunks to cap register pressure; the 24
// logits are accumulated incrementally (k-major) so W2 needs no transpose.
// All weight accesses are wave-uniform -> scalar loads.
__device__ __forceinline__ void eval_g(
    const float* __restrict__ W0, const float* __restrict__ b0,
    const float* __restrict__ W1, const float* __restrict__ b1,
    const float* __restrict__ W2, const float* __restrict__ b2,
    const float* __restrict__ tfs,
    float x0, float x1, float x2,
    float xd0, float xd1, float xd2,
    float& g0, float& g1, float& g2)
{
    v2f lg[NBLEND / 2];
    const v2f* __restrict__ b2v = (const v2f*)b2;
    #pragma unroll
    for (int m2 = 0; m2 < NBLEND / 2; ++m2) lg[m2] = b2v[m2];

    #pragma unroll 1
    for (int hc = 0; hc < 2; ++hc) {
        v2f acc[HHALF / 2];
        const v2f* __restrict__ b1v = (const v2f*)(b1 + hc * HHALF);
        #pragma unroll
        for (int kk = 0; kk < HHALF / 2; ++kk) acc[kk] = b1v[kk];

        // h0[j] on the fly (recomputed per chunk), rank-1 into acc (packed)
        #pragma unroll 2
        for (int j = 0; j < HDIM; ++j) {
            float z = fmaf(x0, W0[j],
                      fmaf(x1, W0[HDIM + j],
                      fmaf(x2, W0[2 * HDIM + j], b0[j])));
            float h = softplus_f(z);
            v2f hv = {h, h};
            const v2f* __restrict__ w1r = (const v2f*)(W1 + j * HDIM + hc * HHALF);
            #pragma unroll
            for (int kk = 0; kk < HHALF / 2; ++kk)
                acc[kk] = VFMA(hv, w1r[kk], acc[kk]);
        }
        #pragma unroll
        for (int kk = 0; kk < HHALF / 2; ++kk) {
            acc[kk].x = softplus_f(acc[kk].x);
            acc[kk].y = softplus_f(acc[kk].y);
        }
        // logits += h1[k] * W2[k,:]  (k-major, W2 rows contiguous)
        #pragma unroll
        for (int k = 0; k < HHALF; ++k) {
            float h1 = (k & 1) ? acc[k >> 1].y : acc[k >> 1].x;
            v2f hv = {h1, h1};
            const v2f* __restrict__ w2r = (const v2f*)(W2 + (hc * HHALF + k) * NBLEND);
            #pragma unroll
            for (int m2 = 0; m2 < NBLEND / 2; ++m2)
                lg[m2] = VFMA(hv, w2r[m2], lg[m2]);
        }
    }

    // online softmax over 24 logits, accumulating blended 3x4 transform T
    float M = -3.0e38f, S = 0.0f;
    v2f T[6];
    #pragma unroll
    for (int t = 0; t < 6; ++t) T[t] = (v2f){0.0f, 0.0f};

    #pragma unroll
    for (int m = 0; m < NBLEND; ++m) {
        float lgm = (m & 1) ? lg[m >> 1].y : lg[m >> 1].x;
        float Mn = fmaxf(M, lgm);
        float c = __expf(M - Mn);
        float e = __expf(lgm - Mn);
        S = fmaf(S, c, e);
        const v2f* __restrict__ tf = (const v2f*)(tfs + m * 12);
        v2f cv = {c, c}, ev = {e, e};
        #pragma unroll
        for (int t = 0; t < 6; ++t) T[t] = VFMA(T[t], cv, ev * tf[t]);
        M = Mn;
    }
    float inv = 1.0f / S;
    float t0 = T[0].x, t1 = T[0].y, t2 = T[1].x, t3 = T[1].y;
    float t4 = T[2].x, t5 = T[2].y, t6 = T[3].x, t7 = T[3].y;
    float t8 = T[4].x, t9 = T[4].y, t10 = T[5].x, t11 = T[5].y;
    g0 = inv * fmaf(t0, x0, fmaf(t1, x1, fmaf(t2,  x2, t3)))  - xd0;
    g1 = inv * fmaf(t4, x0, fmaf(t5, x1, fmaf(t6,  x2, t7)))  - xd1;
    g2 = inv * fmaf(t8, x0, fmaf(t9, x1, fmaf(t10, x2, t11))) - xd2;
}

__global__ __launch_bounds__(256, 3)
void broyden_kernel(const float* __restrict__ xd_p,
                    const float* __restrict__ x_init,
                    const float* __restrict__ Jinv_init,
                    const float* __restrict__ tfs,
                    const float* __restrict__ W0, const float* __restrict__ b0,
                    const float* __restrict__ W1, const float* __restrict__ b1,
                    const float* __restrict__ W2, const float* __restrict__ b2,
                    float* __restrict__ out, int N)
{
    int n = blockIdx.x * blockDim.x + threadIdx.x;
    if (n >= N) return;

    float xd0 = xd_p[n * 3 + 0], xd1 = xd_p[n * 3 + 1], xd2 = xd_p[n * 3 + 2];
    float x0 = x_init[n * 3 + 0], x1 = x_init[n * 3 + 1], x2 = x_init[n * 3 + 2];
    float J[9];
    #pragma unroll
    for (int a = 0; a < 9; ++a) J[a] = Jinv_init[n * 9 + a];

    float g0, g1, g2;
    eval_g(W0, b0, W1, b1, W2, b2, tfs, x0, x1, x2, xd0, xd1, xd2, g0, g1, g2);

    // update = -Jinv @ gx
    float u0 = -(fmaf(J[0], g0, fmaf(J[1], g1, J[2] * g2)));
    float u1 = -(fmaf(J[3], g0, fmaf(J[4], g1, J[5] * g2)));
    float u2 = -(fmaf(J[6], g0, fmaf(J[7], g1, J[8] * g2)));

    float gn_opt = sqrtf(g0 * g0 + g1 * g1 + g2 * g2);
    float xo0 = x0, xo1 = x1, xo2 = x2;
    bool ids = true;   // reference initializes ids = ones(bool)

    for (int step = 0; step < MAX_STEPS; ++step) {
        if (__ballot(ids) == 0ull) break;   // whole wave frozen -> outputs final
        if (ids) {
            float dx0 = u0, dx1 = u1, dx2 = u2;
            x0 += dx0; x1 += dx1; x2 += dx2;

            float ng0, ng1, ng2;
            eval_g(W0, b0, W1, b1, W2, b2, tfs, x0, x1, x2, xd0, xd1, xd2,
                   ng0, ng1, ng2);
            float dg0 = ng0 - g0, dg1 = ng1 - g1, dg2 = ng2 - g2;
            g0 = ng0; g1 = ng1; g2 = ng2;

            float gn = sqrtf(g0 * g0 + g1 * g1 + g2 * g2);
            bool better = gn < gn_opt;           // false for NaN, matches jnp.where
            if (better) { gn_opt = gn; xo0 = x0; xo1 = x1; xo2 = x2; }
            bool ids_new = (gn_opt > CVG_T) && (gn < DVG_T);

            // vT = dx^T @ Jinv   (row vector)
            float vT0 = fmaf(dx0, J[0], fmaf(dx1, J[3], dx2 * J[6]));
            float vT1 = fmaf(dx0, J[1], fmaf(dx1, J[4], dx2 * J[7]));
            float vT2 = fmaf(dx0, J[2], fmaf(dx1, J[5], dx2 * J[8]));
            // a = dx - Jinv @ dgx
            float a0 = dx0 - fmaf(J[0], dg0, fmaf(J[1], dg1, J[2] * dg2));
            float a1 = dx1 - fmaf(J[3], dg0, fmaf(J[4], dg1, J[5] * dg2));
            float a2 = dx2 - fmaf(J[6], dg0, fmaf(J[7], dg1, J[8] * dg2));
            // b = vT @ dgx (scalar), signed-eps guard
            float bb = fmaf(vT0, dg0, fmaf(vT1, dg1, vT2 * dg2));
            bb += (bb >= 0.0f) ? EPS_B : -EPS_B;
            float iu0 = a0 / bb, iu1 = a1 / bb, iu2 = a2 / bb;

            if (ids_new) {   // Jinv += u (outer) vT, masked by NEW ids
                J[0] = fmaf(iu0, vT0, J[0]); J[1] = fmaf(iu0, vT1, J[1]); J[2] = fmaf(iu0, vT2, J[2]);
                J[3] = fmaf(iu1, vT0, J[3]); J[4] = fmaf(iu1, vT1, J[4]); J[5] = fmaf(iu1, vT2, J[5]);
                J[6] = fmaf(iu2, vT0, J[6]); J[7] = fmaf(iu2, vT1, J[7]); J[8] = fmaf(iu2, vT2, J[8]);
            }
            // update = -Jinv @ gx (recompute; unused next step if ids_new false)
            u0 = -(fmaf(J[0], g0, fmaf(J[1], g1, J[2] * g2)));
            u1 = -(fmaf(J[3], g0, fmaf(J[4], g1, J[5] * g2)));
            u2 = -(fmaf(J[6], g0, fmaf(J[7], g1, J[8] * g2)));
            ids = ids_new;
        }
    }

    // outputs: x_opt (N,3,1) | gn_opt (N) | valid (N) as 0.0/1.0
    out[n * 3 + 0] = xo0;
    out[n * 3 + 1] = xo1;
    out[n * 3 + 2] = xo2;
    out[3 * N + n] = gn_opt;
    out[4 * N + n] = (gn_opt < CVG_T) ? 1.0f : 0.0f;
}

extern "C" void kernel_launch(void* const* d_in, const int* in_sizes, int n_in,
                              void* d_out, int out_size, void* d_ws, size_t ws_size,
                              hipStream_t stream) {
    const float* xd     = (const float*)d_in[0];
    const float* x_init = (const float*)d_in[1];
    const float* Jinv   = (const float*)d_in[2];
    const float* tfs    = (const float*)d_in[3];
    const float* W0     = (const float*)d_in[4];
    const float* b0     = (const float*)d_in[5];
    const float* W1     = (const float*)d_in[6];
    const float* b1     = (const float*)d_in[7];
    const float* W2     = (const float*)d_in[8];
    const float* b2     = (const float*)d_in[9];
    float* out = (float*)d_out;

    const int N = in_sizes[0] / 3;
    dim3 block(256);
    dim3 grid((N + 255) / 256);

    hipLaunchKernelGGL(broyden_kernel, grid, block, 0, stream,
                       xd, x_init, Jinv, tfs, W0, b0, W1, b1, W2, b2, out, N);
}